// Round 11
// baseline (109.621 us; speedup 1.0000x reference)
//
#include <hip/hip_runtime.h>
#include <math.h>

#define N_TOK 512
#define DIM   128
#define KDIM  1024
#define EPSF  1e-14f

// ============ Kernel 1: fused projection + transposed-operand write ========
// grid 512 = rowg(64 groups of 8 rows) x sel(8: m=sel>>2 picks mu/sg,
// ch=sel&3 picks 32-col quarter). block 512 (8 waves -> 16 waves/CU).
// Thread: q=t&7 (col quad), rsub=t>>3: row=rsub&7, kq=rsub>>3 (K split 8).
// Each thread: 1 row x 4 cols x 128 k; cross-kq reduce in LDS.
// kq==0 threads also scatter transposed jmuT[d][n] / jsviT[d][n]=(sg,iv).
__global__ __launch_bounds__(512) void projT(
    const float* __restrict__ token, const float* __restrict__ Wmu,
    const float* __restrict__ bmu, const float* __restrict__ Wsg,
    const float* __restrict__ bsg, float* __restrict__ mu,
    float* __restrict__ sg, float* __restrict__ iv,
    float* __restrict__ jmuT, float2* __restrict__ jsviT)
{
    __shared__ float hs[8][KDIM];          // 32 KB relu'd token rows
    __shared__ float4 red[7][8][8];        // 7 KB cross-kq partials
    const int bid = blockIdx.x;
    const int t = threadIdx.x;

    const int rowg = bid >> 3, sel = bid & 7;
    const int m = sel >> 2, ch = sel & 3;

    // stage 8 rows (2048 float4) with relu, coalesced
    {
        const float4* src = (const float4*)(token + (size_t)rowg * 8 * KDIM);
        float4* dst = (float4*)&hs[0][0];
        #pragma unroll
        for (int r = 0; r < 4; ++r) {
            int idx = t + r * 512;
            float4 v = src[idx];
            v.x = fmaxf(v.x, 0.f); v.y = fmaxf(v.y, 0.f);
            v.z = fmaxf(v.z, 0.f); v.w = fmaxf(v.w, 0.f);
            dst[idx] = v;
        }
    }
    __syncthreads();

    const int q = t & 7, rsub = t >> 3;
    const int row = rsub & 7, kq = rsub >> 3;     // kq: 0..7 -> k slice of 128
    const int d = ch * 32 + q * 4;                // col within 128
    const float* __restrict__ W = (m ? Wsg : Wmu) + (size_t)(kq * 128) * DIM + d;
    const float4* hp = (const float4*)(&hs[row][kq * 128]);

    float4 acc = make_float4(0.f, 0.f, 0.f, 0.f);
    #pragma unroll 4
    for (int k4 = 0; k4 < 32; ++k4) {
        float4 h = hp[k4];                         // b128 broadcast per 8 lanes
        const float* wp = W + (size_t)(k4 * 4) * DIM;
        float4 w0 = *(const float4*)(wp);
        float4 w1 = *(const float4*)(wp + DIM);
        float4 w2 = *(const float4*)(wp + 2 * DIM);
        float4 w3 = *(const float4*)(wp + 3 * DIM);
        acc.x = fmaf(h.x, w0.x, acc.x); acc.y = fmaf(h.x, w0.y, acc.y);
        acc.z = fmaf(h.x, w0.z, acc.z); acc.w = fmaf(h.x, w0.w, acc.w);
        acc.x = fmaf(h.y, w1.x, acc.x); acc.y = fmaf(h.y, w1.y, acc.y);
        acc.z = fmaf(h.y, w1.z, acc.z); acc.w = fmaf(h.y, w1.w, acc.w);
        acc.x = fmaf(h.z, w2.x, acc.x); acc.y = fmaf(h.z, w2.y, acc.y);
        acc.z = fmaf(h.z, w2.z, acc.z); acc.w = fmaf(h.z, w2.w, acc.w);
        acc.x = fmaf(h.w, w3.x, acc.x); acc.y = fmaf(h.w, w3.y, acc.y);
        acc.z = fmaf(h.w, w3.z, acc.z); acc.w = fmaf(h.w, w3.w, acc.w);
    }

    if (kq > 0) red[kq - 1][row][q] = acc;
    __syncthreads();
    if (kq == 0) {
        #pragma unroll
        for (int s = 0; s < 7; ++s) {
            float4 r = red[s][row][q];
            acc.x += r.x; acc.y += r.y; acc.z += r.z; acc.w += r.w;
        }
        const int rowi = rowg * 8 + row;
        if (m == 0) {
            float4 b = *(const float4*)(bmu + d);
            acc.x += b.x; acc.y += b.y; acc.z += b.z; acc.w += b.w;
            *(float4*)(mu + (size_t)rowi * DIM + d) = acc;
            jmuT[(size_t)(d + 0) * N_TOK + rowi] = acc.x;
            jmuT[(size_t)(d + 1) * N_TOK + rowi] = acc.y;
            jmuT[(size_t)(d + 2) * N_TOK + rowi] = acc.z;
            jmuT[(size_t)(d + 3) * N_TOK + rowi] = acc.w;
        } else {
            float4 b = *(const float4*)(bsg + d);
            float x0 = acc.x + b.x, x1 = acc.y + b.y;
            float x2 = acc.z + b.z, x3 = acc.w + b.w;
            float4 e, vv;
            e.x = (x0 > 0.f ? x0 : expm1f(x0)) + 1.0f + EPSF;
            e.y = (x1 > 0.f ? x1 : expm1f(x1)) + 1.0f + EPSF;
            e.z = (x2 > 0.f ? x2 : expm1f(x2)) + 1.0f + EPSF;
            e.w = (x3 > 0.f ? x3 : expm1f(x3)) + 1.0f + EPSF;
            vv.x = 1.0f / e.x; vv.y = 1.0f / e.y;
            vv.z = 1.0f / e.z; vv.w = 1.0f / e.w;
            *(float4*)(sg + (size_t)rowi * DIM + d) = e;
            *(float4*)(iv + (size_t)rowi * DIM + d) = vv;
            jsviT[(size_t)(d + 0) * N_TOK + rowi] = make_float2(e.x, vv.x);
            jsviT[(size_t)(d + 1) * N_TOK + rowi] = make_float2(e.y, vv.y);
            jsviT[(size_t)(d + 2) * N_TOK + rowi] = make_float2(e.z, vv.z);
            jsviT[(size_t)(d + 3) * N_TOK + rowi] = make_float2(e.w, vv.w);
        }
    }
}

// ============ Kernel 2: pairwise sym-KL + masked row partial sums ==========
// grid 512 = ig(32 groups of 16 i-rows) x jg(16 groups of 32 j).
// block 512 (8 waves -> 16 waves/CU): thread t -> jl=t&31, il=t>>5;
// ONE pair per thread (shorter dep chains, 2x waves vs round 9).
// i-side: LDS row-major, broadcast b128 per half-wave. j-side: transposed
// coalesced per-lane loads (jmuT scalar + jsviT float2, L1/L2-resident).
// e_ij = exp(D - 0.5*acc), acc = sum_d [(s_j+dm^2)*v_i + (s_i+dm^2)*v_j].
__global__ __launch_bounds__(512) void pair_kernel(
    const float* __restrict__ mu, const float* __restrict__ sg,
    const float* __restrict__ iv, const float* __restrict__ jmuT,
    const float2* __restrict__ jsviT, const int* __restrict__ labels,
    const int* __restrict__ mask, float* __restrict__ gpart)
{
    __shared__ float si[3][16][DIM];       // 24 KB
    __shared__ int slab[16], svalid[16];
    const int ig = blockIdx.x >> 4, jg = blockIdx.x & 15;
    const int i0 = ig * 16, j0 = jg * 32;
    const int t = threadIdx.x;

    {   // stage 16 i-rows: exactly 512 float4 slots per array
        int row = t >> 5, kq = t & 31;
        size_t off = (size_t)(i0 + row) * DIM + kq * 4;
        ((float4*)&si[0][0][0])[t] = *(const float4*)(mu + off);
        ((float4*)&si[1][0][0])[t] = *(const float4*)(sg + off);
        ((float4*)&si[2][0][0])[t] = *(const float4*)(iv + off);
    }
    if (t < 16) {
        int lab = labels[i0 + t];
        slab[t] = lab;
        svalid[t] = (mask[i0 + t] == 1 && lab > 0) ? 1 : 0;
    }
    __syncthreads();

    const int jl = t & 31, il = t >> 5;    // il: 0..15
    const int j = j0 + jl;
    const int labj = labels[j];
    const bool validj = (mask[j] == 1) && (labj > 0);

    const float*  pmT = jmuT  + j;         // stride N_TOK per d
    const float2* psT = jsviT + j;

    float acc = 0.f;
    float mn = 1e30f;

    #pragma unroll 4
    for (int q = 0; q < 32; ++q) {
        const int d0 = q * 4;
        float  jm0 = pmT[(size_t)(d0 + 0) * N_TOK];
        float  jm1 = pmT[(size_t)(d0 + 1) * N_TOK];
        float  jm2 = pmT[(size_t)(d0 + 2) * N_TOK];
        float  jm3 = pmT[(size_t)(d0 + 3) * N_TOK];
        float2 sv0 = psT[(size_t)(d0 + 0) * N_TOK];   // (sg_j, iv_j)
        float2 sv1 = psT[(size_t)(d0 + 1) * N_TOK];
        float2 sv2 = psT[(size_t)(d0 + 2) * N_TOK];
        float2 sv3 = psT[(size_t)(d0 + 3) * N_TOK];

        float4 bm = *(const float4*)(&si[0][il][d0]);
        float4 bs = *(const float4*)(&si[1][il][d0]);
        float4 bv = *(const float4*)(&si[2][il][d0]);

        float dm;
        dm = bm.x - jm0; acc = fmaf(fmaf(dm, dm, sv0.x), bv.x, fmaf(fmaf(dm, dm, bs.x), sv0.y, acc)); mn = fminf(mn, fabsf(dm));
        dm = bm.y - jm1; acc = fmaf(fmaf(dm, dm, sv1.x), bv.y, fmaf(fmaf(dm, dm, bs.y), sv1.y, acc)); mn = fminf(mn, fabsf(dm));
        dm = bm.z - jm2; acc = fmaf(fmaf(dm, dm, sv2.x), bv.z, fmaf(fmaf(dm, dm, bs.z), sv2.y, acc)); mn = fminf(mn, fabsf(dm));
        dm = bm.w - jm3; acc = fmaf(fmaf(dm, dm, sv3.x), bv.w, fmaf(fmaf(dm, dm, bs.w), sv3.y, acc)); mn = fminf(mn, fabsf(dm));
    }

    float e = expf(128.0f - 0.5f * acc);
    bool pv = validj && (svalid[il] != 0) && (mn != 0.0f);
    bool sm = pv && (labj == slab[il]);
    float dd = pv ? e : 0.f, nn = sm ? e : 0.f, cc = sm ? 1.f : 0.f;

    // reduce over the 32 j-lanes (masks < 32 stay within half-wave)
    #pragma unroll
    for (int m = 1; m < 32; m <<= 1) {
        cc += __shfl_xor(cc, m); nn += __shfl_xor(nn, m); dd += __shfl_xor(dd, m);
    }
    if (jl == 0) {
        float* pa = gpart + ((size_t)jg * N_TOK + i0 + il) * 3;
        pa[0] = cc; pa[1] = nn; pa[2] = dd;
    }
}

// ============ Kernel 3: final loss ============
__global__ __launch_bounds__(512) void final_kernel(
    const float* __restrict__ gpart, float* __restrict__ out)
{
    __shared__ float redL[8], redI[8];
    const int t = threadIdx.x;           // 512 threads = 512 rows
    float c = 0.f, nm = 0.f, dn = 0.f;
    #pragma unroll
    for (int jg = 0; jg < 16; ++jg) {
        const float* p = gpart + ((size_t)jg * N_TOK + t) * 3;
        c += p[0]; nm += p[1]; dn += p[2];
    }
    const bool inc = c > 0.5f;
    float lf = inc ? (-logf(nm) + logf(dn) + logf(c)) : 0.f;
    float fi = inc ? 1.f : 0.f;
    #pragma unroll
    for (int m = 1; m < 64; m <<= 1) {
        lf += __shfl_xor(lf, m);
        fi += __shfl_xor(fi, m);
    }
    if ((t & 63) == 0) { redL[t >> 6] = lf; redI[t >> 6] = fi; }
    __syncthreads();
    if (t == 0) {
        float L = 0.f, I = 0.f;
        #pragma unroll
        for (int w = 0; w < 8; ++w) { L += redL[w]; I += redI[w]; }
        out[0] = L / fmaxf(I, 1.0f);
    }
}

// ============ launcher ============
extern "C" void kernel_launch(void* const* d_in, const int* in_sizes, int n_in,
                              void* d_out, int out_size, void* d_ws, size_t ws_size,
                              hipStream_t stream) {
    const float* token  = (const float*)d_in[0];
    const int*   labels = (const int*)d_in[1];
    const int*   mask   = (const int*)d_in[2];
    const float* Wmu    = (const float*)d_in[3];
    const float* bmu    = (const float*)d_in[4];
    const float* Wsg    = (const float*)d_in[5];
    const float* bsg    = (const float*)d_in[6];

    float*  ws    = (float*)d_ws;
    float*  mu    = ws;                        // 65,536
    float*  sg    = mu + 65536;
    float*  iv    = sg + 65536;
    float*  jmuT  = iv + 65536;                // 65,536
    float2* jsviT = (float2*)(jmuT + 65536);   // 65,536 float2
    float*  gpart = (float*)(jsviT + 65536);   // 16*512*3 = 24,576

    projT<<<512, 512, 0, stream>>>(token, Wmu, bmu, Wsg, bsg, mu, sg, iv,
                                   jmuT, jsviT);
    pair_kernel<<<512, 512, 0, stream>>>(mu, sg, iv, jmuT, jsviT, labels, mask,
                                         gpart);
    final_kernel<<<1, 512, 0, stream>>>(gpart, (float*)d_out);
}

// Round 12
// 108.742 us; speedup vs baseline: 1.0081x; 1.0081x over previous
//
#include <hip/hip_runtime.h>
#include <math.h>

#define N_TOK 512
#define DIM   128
#define KDIM  1024
#define EPSF  1e-14f

// ============ Kernel 1: fused projection + transposed-operand write ========
// (unchanged from round 11 — measured passing, deterministic)
__global__ __launch_bounds__(512) void projT(
    const float* __restrict__ token, const float* __restrict__ Wmu,
    const float* __restrict__ bmu, const float* __restrict__ Wsg,
    const float* __restrict__ bsg, float* __restrict__ mu,
    float* __restrict__ sg, float* __restrict__ iv,
    float* __restrict__ jmuT, float2* __restrict__ jsviT)
{
    __shared__ float hs[8][KDIM];          // 32 KB relu'd token rows
    __shared__ float4 red[7][8][8];        // 7 KB cross-kq partials
    const int bid = blockIdx.x;
    const int t = threadIdx.x;

    const int rowg = bid >> 3, sel = bid & 7;
    const int m = sel >> 2, ch = sel & 3;

    {
        const float4* src = (const float4*)(token + (size_t)rowg * 8 * KDIM);
        float4* dst = (float4*)&hs[0][0];
        #pragma unroll
        for (int r = 0; r < 4; ++r) {
            int idx = t + r * 512;
            float4 v = src[idx];
            v.x = fmaxf(v.x, 0.f); v.y = fmaxf(v.y, 0.f);
            v.z = fmaxf(v.z, 0.f); v.w = fmaxf(v.w, 0.f);
            dst[idx] = v;
        }
    }
    __syncthreads();

    const int q = t & 7, rsub = t >> 3;
    const int row = rsub & 7, kq = rsub >> 3;     // kq: 0..7 -> k slice of 128
    const int d = ch * 32 + q * 4;
    const float* __restrict__ W = (m ? Wsg : Wmu) + (size_t)(kq * 128) * DIM + d;
    const float4* hp = (const float4*)(&hs[row][kq * 128]);

    float4 acc = make_float4(0.f, 0.f, 0.f, 0.f);
    #pragma unroll 4
    for (int k4 = 0; k4 < 32; ++k4) {
        float4 h = hp[k4];
        const float* wp = W + (size_t)(k4 * 4) * DIM;
        float4 w0 = *(const float4*)(wp);
        float4 w1 = *(const float4*)(wp + DIM);
        float4 w2 = *(const float4*)(wp + 2 * DIM);
        float4 w3 = *(const float4*)(wp + 3 * DIM);
        acc.x = fmaf(h.x, w0.x, acc.x); acc.y = fmaf(h.x, w0.y, acc.y);
        acc.z = fmaf(h.x, w0.z, acc.z); acc.w = fmaf(h.x, w0.w, acc.w);
        acc.x = fmaf(h.y, w1.x, acc.x); acc.y = fmaf(h.y, w1.y, acc.y);
        acc.z = fmaf(h.y, w1.z, acc.z); acc.w = fmaf(h.y, w1.w, acc.w);
        acc.x = fmaf(h.z, w2.x, acc.x); acc.y = fmaf(h.z, w2.y, acc.y);
        acc.z = fmaf(h.z, w2.z, acc.z); acc.w = fmaf(h.z, w2.w, acc.w);
        acc.x = fmaf(h.w, w3.x, acc.x); acc.y = fmaf(h.w, w3.y, acc.y);
        acc.z = fmaf(h.w, w3.z, acc.z); acc.w = fmaf(h.w, w3.w, acc.w);
    }

    if (kq > 0) red[kq - 1][row][q] = acc;
    __syncthreads();
    if (kq == 0) {
        #pragma unroll
        for (int s = 0; s < 7; ++s) {
            float4 r = red[s][row][q];
            acc.x += r.x; acc.y += r.y; acc.z += r.z; acc.w += r.w;
        }
        const int rowi = rowg * 8 + row;
        if (m == 0) {
            float4 b = *(const float4*)(bmu + d);
            acc.x += b.x; acc.y += b.y; acc.z += b.z; acc.w += b.w;
            *(float4*)(mu + (size_t)rowi * DIM + d) = acc;
            jmuT[(size_t)(d + 0) * N_TOK + rowi] = acc.x;
            jmuT[(size_t)(d + 1) * N_TOK + rowi] = acc.y;
            jmuT[(size_t)(d + 2) * N_TOK + rowi] = acc.z;
            jmuT[(size_t)(d + 3) * N_TOK + rowi] = acc.w;
        } else {
            float4 b = *(const float4*)(bsg + d);
            float x0 = acc.x + b.x, x1 = acc.y + b.y;
            float x2 = acc.z + b.z, x3 = acc.w + b.w;
            float4 e, vv;
            e.x = (x0 > 0.f ? x0 : expm1f(x0)) + 1.0f + EPSF;
            e.y = (x1 > 0.f ? x1 : expm1f(x1)) + 1.0f + EPSF;
            e.z = (x2 > 0.f ? x2 : expm1f(x2)) + 1.0f + EPSF;
            e.w = (x3 > 0.f ? x3 : expm1f(x3)) + 1.0f + EPSF;
            vv.x = 1.0f / e.x; vv.y = 1.0f / e.y;
            vv.z = 1.0f / e.z; vv.w = 1.0f / e.w;
            *(float4*)(sg + (size_t)rowi * DIM + d) = e;
            *(float4*)(iv + (size_t)rowi * DIM + d) = vv;
            jsviT[(size_t)(d + 0) * N_TOK + rowi] = make_float2(e.x, vv.x);
            jsviT[(size_t)(d + 1) * N_TOK + rowi] = make_float2(e.y, vv.y);
            jsviT[(size_t)(d + 2) * N_TOK + rowi] = make_float2(e.z, vv.z);
            jsviT[(size_t)(d + 3) * N_TOK + rowi] = make_float2(e.w, vv.w);
        }
    }
}

// ============ Kernel 2: SYMMETRIC pairwise sym-KL (upper triangle only) =====
// 16x16 token tiles; grid 528 = triangle {(R,C): 0<=R<=C<32}; block 256.
// Thread: il=t>>4 (i row in tile R), jl=t&15 (j col in tile C); ONE pair.
// e, masks are symmetric -> each off-diagonal block emits row-partials for
// BOTH tiles: i-path (reduce over jl) -> gpart[C][i], mirror (reduce over
// il via shfl + LDS) -> gpart[R][j]. Diagonal blocks emit i-path only.
// Every gpart slot written exactly once -> deterministic, no atomics.
__global__ __launch_bounds__(256) void pair_sym(
    const float* __restrict__ mu, const float* __restrict__ sg,
    const float* __restrict__ iv, const float* __restrict__ jmuT,
    const float2* __restrict__ jsviT, const int* __restrict__ labels,
    const int* __restrict__ mask, float* __restrict__ gpart)
{
    __shared__ float si[3][16][DIM];       // 24 KB i-tile
    __shared__ float mred[4][16][3];       // mirror cross-wave partials
    __shared__ int slab[16], svalid[16];
    const int t = threadIdx.x;

    // triangle index -> (R, C), S(R) = 32R - R(R-1)/2
    const int k = blockIdx.x;
    int R = (int)((65.0f - sqrtf(4225.0f - 8.0f * (float)k)) * 0.5f);
    R = R < 0 ? 0 : (R > 31 ? 31 : R);
    while (R > 0 && (32 * R - R * (R - 1) / 2) > k) --R;
    while (R < 31 && (32 * (R + 1) - (R + 1) * R / 2) <= k) ++R;
    const int C = R + (k - (32 * R - R * (R - 1) / 2));
    const int i0 = R * 16, j0 = C * 16;
    const bool diag = (R == C);

    {   // stage 16 i-rows: 512 float4 slots per array, 256 threads x 2 reps
        #pragma unroll
        for (int rep = 0; rep < 2; ++rep) {
            int f = t + rep * 256;
            int row = f >> 5, kq = f & 31;
            size_t off = (size_t)(i0 + row) * DIM + kq * 4;
            ((float4*)&si[0][0][0])[f] = *(const float4*)(mu + off);
            ((float4*)&si[1][0][0])[f] = *(const float4*)(sg + off);
            ((float4*)&si[2][0][0])[f] = *(const float4*)(iv + off);
        }
    }
    if (t < 16) {
        int lab = labels[i0 + t];
        slab[t] = lab;
        svalid[t] = (mask[i0 + t] == 1 && lab > 0) ? 1 : 0;
    }
    __syncthreads();

    const int jl = t & 15, il = t >> 4;    // il: 0..15
    const int j = j0 + jl;
    const int labj = labels[j];
    const bool validj = (mask[j] == 1) && (labj > 0);

    const float*  pmT = jmuT  + j;         // stride N_TOK per d
    const float2* psT = jsviT + j;

    float acc = 0.f;
    float mn = 1e30f;

    #pragma unroll 4
    for (int q = 0; q < 32; ++q) {
        const int d0 = q * 4;
        float  jm0 = pmT[(size_t)(d0 + 0) * N_TOK];
        float  jm1 = pmT[(size_t)(d0 + 1) * N_TOK];
        float  jm2 = pmT[(size_t)(d0 + 2) * N_TOK];
        float  jm3 = pmT[(size_t)(d0 + 3) * N_TOK];
        float2 sv0 = psT[(size_t)(d0 + 0) * N_TOK];   // (sg_j, iv_j)
        float2 sv1 = psT[(size_t)(d0 + 1) * N_TOK];
        float2 sv2 = psT[(size_t)(d0 + 2) * N_TOK];
        float2 sv3 = psT[(size_t)(d0 + 3) * N_TOK];

        float4 bm = *(const float4*)(&si[0][il][d0]);
        float4 bs = *(const float4*)(&si[1][il][d0]);
        float4 bv = *(const float4*)(&si[2][il][d0]);

        float dm;
        dm = bm.x - jm0; acc = fmaf(fmaf(dm, dm, sv0.x), bv.x, fmaf(fmaf(dm, dm, bs.x), sv0.y, acc)); mn = fminf(mn, fabsf(dm));
        dm = bm.y - jm1; acc = fmaf(fmaf(dm, dm, sv1.x), bv.y, fmaf(fmaf(dm, dm, bs.y), sv1.y, acc)); mn = fminf(mn, fabsf(dm));
        dm = bm.z - jm2; acc = fmaf(fmaf(dm, dm, sv2.x), bv.z, fmaf(fmaf(dm, dm, bs.z), sv2.y, acc)); mn = fminf(mn, fabsf(dm));
        dm = bm.w - jm3; acc = fmaf(fmaf(dm, dm, sv3.x), bv.w, fmaf(fmaf(dm, dm, bs.w), sv3.y, acc)); mn = fminf(mn, fabsf(dm));
    }

    float e = expf(128.0f - 0.5f * acc);
    bool pv = validj && (svalid[il] != 0) && (mn != 0.0f);
    bool sm = pv && (labj == slab[il]);
    float dd = pv ? e : 0.f, nn = sm ? e : 0.f, cc = sm ? 1.f : 0.f;

    // ---- i-path: reduce over jl (16 lanes; masks stay in 16-groups) ----
    float ic = cc, in = nn, id = dd;
    #pragma unroll
    for (int m = 1; m < 16; m <<= 1) {
        ic += __shfl_xor(ic, m); in += __shfl_xor(in, m); id += __shfl_xor(id, m);
    }
    if (jl == 0) {
        float* pa = gpart + ((size_t)C * N_TOK + i0 + il) * 3;
        pa[0] = ic; pa[1] = in; pa[2] = id;
    }

    // ---- mirror path: reduce over il (skip on diagonal blocks) ----
    if (!diag) {
        float mc = cc, mm = nn, md = dd;
        mc += __shfl_xor(mc, 16); mm += __shfl_xor(mm, 16); md += __shfl_xor(md, 16);
        mc += __shfl_xor(mc, 32); mm += __shfl_xor(mm, 32); md += __shfl_xor(md, 32);
        const int w = t >> 6;              // wave 0..3 holds il group 4w..4w+3
        if ((t & 63) < 16) {
            mred[w][jl][0] = mc; mred[w][jl][1] = mm; mred[w][jl][2] = md;
        }
        __syncthreads();
        if (t < 16) {
            float c4 = mred[0][t][0] + mred[1][t][0] + mred[2][t][0] + mred[3][t][0];
            float n4 = mred[0][t][1] + mred[1][t][1] + mred[2][t][1] + mred[3][t][1];
            float d4 = mred[0][t][2] + mred[1][t][2] + mred[2][t][2] + mred[3][t][2];
            float* pb = gpart + ((size_t)R * N_TOK + j0 + t) * 3;
            pb[0] = c4; pb[1] = n4; pb[2] = d4;
        }
    }
}

// ============ Kernel 3: final loss (32 col-group slots) ============
__global__ __launch_bounds__(512) void final_kernel(
    const float* __restrict__ gpart, float* __restrict__ out)
{
    __shared__ float redL[8], redI[8];
    const int t = threadIdx.x;           // 512 threads = 512 rows
    float c = 0.f, nm = 0.f, dn = 0.f;
    #pragma unroll
    for (int g = 0; g < 32; ++g) {
        const float* p = gpart + ((size_t)g * N_TOK + t) * 3;
        c += p[0]; nm += p[1]; dn += p[2];
    }
    const bool inc = c > 0.5f;
    float lf = inc ? (-logf(nm) + logf(dn) + logf(c)) : 0.f;
    float fi = inc ? 1.f : 0.f;
    #pragma unroll
    for (int m = 1; m < 64; m <<= 1) {
        lf += __shfl_xor(lf, m);
        fi += __shfl_xor(fi, m);
    }
    if ((t & 63) == 0) { redL[t >> 6] = lf; redI[t >> 6] = fi; }
    __syncthreads();
    if (t == 0) {
        float L = 0.f, I = 0.f;
        #pragma unroll
        for (int w = 0; w < 8; ++w) { L += redL[w]; I += redI[w]; }
        out[0] = L / fmaxf(I, 1.0f);
    }
}

// ============ launcher ============
extern "C" void kernel_launch(void* const* d_in, const int* in_sizes, int n_in,
                              void* d_out, int out_size, void* d_ws, size_t ws_size,
                              hipStream_t stream) {
    const float* token  = (const float*)d_in[0];
    const int*   labels = (const int*)d_in[1];
    const int*   mask   = (const int*)d_in[2];
    const float* Wmu    = (const float*)d_in[3];
    const float* bmu    = (const float*)d_in[4];
    const float* Wsg    = (const float*)d_in[5];
    const float* bsg    = (const float*)d_in[6];

    float*  ws    = (float*)d_ws;
    float*  mu    = ws;                        // 65,536
    float*  sg    = mu + 65536;
    float*  iv    = sg + 65536;
    float*  jmuT  = iv + 65536;                // 65,536
    float2* jsviT = (float2*)(jmuT + 65536);   // 65,536 float2
    float*  gpart = (float*)(jsviT + 65536);   // 32*512*3 = 49,152

    projT<<<512, 512, 0, stream>>>(token, Wmu, bmu, Wsg, bsg, mu, sg, iv,
                                   jmuT, jsviT);
    pair_sym<<<528, 256, 0, stream>>>(mu, sg, iv, jmuT, jsviT, labels, mask,
                                      gpart);
    final_kernel<<<1, 512, 0, stream>>>(gpart, (float*)d_out);
}